// Round 1
// baseline (36.238 us; speedup 1.0000x reference)
//
#include <hip/hip_runtime.h>

// QuantumTTEmbedding: TT-factorized embedding lookup.
// N = B*S tokens; id -> (i,j,k) = (id/1600, (id/40)%40, id%40).
// Per half (real/imag):
//   g1[d][r]   = c1[0][i][d][r]          (c1: [1,20,4,4])
//   g2[r][f][s]= c2[r][j][f][s]          (c2: [4,40,4,4])
//   g3[s][e]   = c3[s][k][e][0]          (c3: [4,40,8,1])
//   temp[d][f][s] = sum_r g1[d][r]*g2[r][f][s]
//   out[d][f][e]  = sum_s temp[d][f][s]*g3[s][e]
// Output: [N][256] f32, real half then imag half, flat (d*32+f*8+e).

#define V1 20
#define V2 40
#define V3 40
#define D1 4
#define D2 4
#define D3 8
#define RNK 4

#define C1_SZ (V1*D1*RNK)          // 320 floats
#define C2_SZ (RNK*V2*D2*RNK)      // 2560 floats
#define C3_SZ (RNK*V3*D3)          // 1280 floats
#define HALF_SZ (C1_SZ + C2_SZ + C3_SZ)   // 4160
#define IMAG_OFF (HALF_SZ + 16)    // +16 floats: imag region bank-offset by 16
#define LDS_FLOATS (IMAG_OFF + HALF_SZ)   // 8336 floats = 33.4 KB

__global__ __launch_bounds__(256) void tt_embed_kernel(
    const int* __restrict__ ids,
    const float* __restrict__ cr1, const float* __restrict__ cr2, const float* __restrict__ cr3,
    const float* __restrict__ ci1, const float* __restrict__ ci2, const float* __restrict__ ci3,
    float* __restrict__ out, int N)
{
    __shared__ float lds[LDS_FLOATS];

    // ---- stage cores into LDS (once per block) ----
    for (int idx = threadIdx.x; idx < C1_SZ; idx += 256) {
        lds[idx]            = cr1[idx];
        lds[IMAG_OFF + idx] = ci1[idx];
    }
    for (int idx = threadIdx.x; idx < C2_SZ; idx += 256) {
        lds[C1_SZ + idx]            = cr2[idx];
        lds[IMAG_OFF + C1_SZ + idx] = ci2[idx];
    }
    for (int idx = threadIdx.x; idx < C3_SZ; idx += 256) {
        lds[C1_SZ + C2_SZ + idx]            = cr3[idx];
        lds[IMAG_OFF + C1_SZ + C2_SZ + idx] = ci3[idx];
    }
    __syncthreads();

    // ---- lane decomposition: one wave per token ----
    // lane = half*32 + q ; q -> (d, f, e0): outputs q*4 .. q*4+3 of the half.
    const int lane = threadIdx.x & 63;
    const int half = lane >> 5;          // 0 = real, 1 = imag
    const int q    = lane & 31;
    const int d    = q >> 3;             // 0..3
    const int f    = (q >> 1) & 3;       // 0..3
    const int e0   = (q & 1) * 4;        // 0 or 4

    const float* base = lds + half * IMAG_OFF;
    const float* B1 = base + d * RNK;                    // + i*16 -> g1[d][0..3]
    const float* B2 = base + C1_SZ + f * RNK;            // + r*640 + j*16 -> g2[r][f][0..3]
    const float* B3 = base + C1_SZ + C2_SZ + e0;         // + s*320 + k*8 -> g3[s][e0..e0+3]

    const int wid = (int)((blockIdx.x * blockDim.x + threadIdx.x) >> 6);
    const int nw  = (int)((gridDim.x * blockDim.x) >> 6);

    for (int t = wid; t < N; t += nw) {
        const int id = ids[t];
        const int k  = id % V3;
        const int ij = id / V3;
        const int j  = ij % V2;
        const int i  = ij / V2;

        // g1 row for this lane's d
        const float4 g1 = *reinterpret_cast<const float4*>(B1 + i * (D1 * RNK));
        const float g1a[4] = { g1.x, g1.y, g1.z, g1.w };

        // temp[s] = sum_r g1[r] * g2[r][f][s]
        float tmp[4] = {0.f, 0.f, 0.f, 0.f};
        const float* p2 = B2 + j * (D2 * RNK);
        #pragma unroll
        for (int r = 0; r < 4; ++r) {
            const float4 g2 = *reinterpret_cast<const float4*>(p2 + r * (V2 * D2 * RNK));
            tmp[0] += g1a[r] * g2.x;
            tmp[1] += g1a[r] * g2.y;
            tmp[2] += g1a[r] * g2.z;
            tmp[3] += g1a[r] * g2.w;
        }

        // out[e] = sum_s temp[s] * g3[s][e0+e]
        float4 o = make_float4(0.f, 0.f, 0.f, 0.f);
        const float* p3 = B3 + k * D3;
        #pragma unroll
        for (int s = 0; s < 4; ++s) {
            const float4 g3 = *reinterpret_cast<const float4*>(p3 + s * (V3 * D3));
            o.x += tmp[s] * g3.x;
            o.y += tmp[s] * g3.y;
            o.z += tmp[s] * g3.z;
            o.w += tmp[s] * g3.w;
        }

        *reinterpret_cast<float4*>(out + (size_t)t * 256 + lane * 4) = o;
    }
}

extern "C" void kernel_launch(void* const* d_in, const int* in_sizes, int n_in,
                              void* d_out, int out_size, void* d_ws, size_t ws_size,
                              hipStream_t stream) {
    const int*   ids = (const int*)d_in[0];
    const float* cr1 = (const float*)d_in[1];
    const float* cr2 = (const float*)d_in[2];
    const float* cr3 = (const float*)d_in[3];
    const float* ci1 = (const float*)d_in[4];
    const float* ci2 = (const float*)d_in[5];
    const float* ci3 = (const float*)d_in[6];
    float* out = (float*)d_out;

    const int N = in_sizes[0];          // B*S tokens
    const int blocks = 1024;            // grid-stride; 4 waves/block -> 4096 waves

    tt_embed_kernel<<<blocks, 256, 0, stream>>>(ids, cr1, cr2, cr3, ci1, ci2, ci3, out, N);
}

// Round 2
// 30.570 us; speedup vs baseline: 1.1854x; 1.1854x over previous
//
#include <hip/hip_runtime.h>

// QuantumTTEmbedding: TT-factorized embedding lookup.
// id -> (i,j,k) = (id/1600, (id/40)%40, id%40).
// Per half (real/imag):
//   out[d][f][e] = sum_{r,s} c1[0][i][d][r] * c2[r][j][f][s] * c3[s][k][e][0]
// Output [N][256] f32: real 128 then imag 128, flat (d*32+f*8+e).

#define V1 20
#define V2 40
#define V3 40
#define D1 4
#define D2 4
#define D3 8
#define RNK 4

#define C1_SZ (V1*D1*RNK)          // 320 floats
#define C2_SZ (RNK*V2*D2*RNK)      // 2560 floats
#define C3_SZ (RNK*V3*D3)          // 1280 floats
#define HALF_SZ (C1_SZ + C2_SZ + C3_SZ)   // 4160
#define IMAG_OFF (HALF_SZ + 16)    // 4176: imag region bank-offset by 16 floats
#define LDS_FLOATS (IMAG_OFF + HALF_SZ)   // 8336 floats = 33.4 KB

#define TPW 16                     // tokens per wave
#define BLOCK 512                  // 8 waves/block; 4 blocks/CU -> 32 waves/CU

__global__ __launch_bounds__(BLOCK, 8) void tt_embed_kernel(
    const int* __restrict__ ids,
    const float* __restrict__ cr1, const float* __restrict__ cr2, const float* __restrict__ cr3,
    const float* __restrict__ ci1, const float* __restrict__ ci2, const float* __restrict__ ci3,
    float* __restrict__ out, int N)
{
    __shared__ __align__(16) float lds[LDS_FLOATS];

    // ---- stage cores into LDS, float4-vectorized ----
    {
        float4*       l4r = (float4*)lds;
        float4*       l4i = (float4*)(lds + IMAG_OFF);
        const float4* s1r = (const float4*)cr1; const float4* s1i = (const float4*)ci1;
        const float4* s2r = (const float4*)cr2; const float4* s2i = (const float4*)ci2;
        const float4* s3r = (const float4*)cr3; const float4* s3i = (const float4*)ci3;
        for (int idx = threadIdx.x; idx < C1_SZ/4; idx += BLOCK) {
            l4r[idx] = s1r[idx];
            l4i[idx] = s1i[idx];
        }
        for (int idx = threadIdx.x; idx < C2_SZ/4; idx += BLOCK) {
            l4r[C1_SZ/4 + idx] = s2r[idx];
            l4i[C1_SZ/4 + idx] = s2i[idx];
        }
        for (int idx = threadIdx.x; idx < C3_SZ/4; idx += BLOCK) {
            l4r[(C1_SZ+C2_SZ)/4 + idx] = s3r[idx];
            l4i[(C1_SZ+C2_SZ)/4 + idx] = s3i[idx];
        }
    }
    __syncthreads();

    // ---- lane decomposition: one wave per token, 4 outputs per lane ----
    const int lane = threadIdx.x & 63;
    const int half = lane >> 5;          // 0 = real, 1 = imag
    const int q    = lane & 31;
    const int d    = q >> 3;             // 0..3
    const int f    = (q >> 1) & 3;       // 0..3
    const int e0   = (q & 1) * 4;        // 0 or 4

    const float* base = lds + half * IMAG_OFF;
    const float* B1 = base + d * RNK;                    // + i*16 -> g1[d][0..3]
    const float* B2 = base + C1_SZ + f * RNK;            // + r*640 + j*16 -> g2[r][f][0..3]
    const float* B3 = base + C1_SZ + C2_SZ + e0;         // + s*320 + k*8 -> g3[s][e0..e0+3]

    const int wid = blockIdx.x * (BLOCK / 64) + (threadIdx.x >> 6);
    const int t0  = wid * TPW;

    // ---- preload this wave's 16 token ids; pack LDS float-offsets per lane ----
    int packed = 0;
    if (lane < TPW) {
        const int t = t0 + lane;
        if (t < N) {
            const int id = ids[t];
            const int k  = id % V3;
            const int ij = id / V3;
            const int j  = ij % V2;
            const int i  = ij / V2;
            // i*16 <= 304 (9 bits) | j*16 <= 624 (10 bits) | k*8 <= 312 (9 bits)
            packed = (i * (D1*RNK)) | ((j * (D2*RNK)) << 9) | ((k * D3) << 19);
        }
    }

    float* outp = out + (size_t)t0 * 256 + lane * 4;

    #pragma unroll 1
    for (int it = 0; it < TPW; ++it) {
        if (t0 + it >= N) break;
        const int p  = __builtin_amdgcn_readlane(packed, it);  // SGPR broadcast
        const int io = p & 0x1ff;
        const int jo = (p >> 9) & 0x3ff;
        const int ko = (p >> 19);

        // g1 row for this lane's d
        const float4 g1 = *reinterpret_cast<const float4*>(B1 + io);

        // temp[s] = sum_r g1[r] * g2[r][f][s]
        const float* p2 = B2 + jo;
        const float4 a0 = *reinterpret_cast<const float4*>(p2);
        const float4 a1 = *reinterpret_cast<const float4*>(p2 +     V2*D2*RNK);
        const float4 a2 = *reinterpret_cast<const float4*>(p2 + 2 * V2*D2*RNK);
        const float4 a3 = *reinterpret_cast<const float4*>(p2 + 3 * V2*D2*RNK);
        const float tmp0 = g1.x*a0.x + g1.y*a1.x + g1.z*a2.x + g1.w*a3.x;
        const float tmp1 = g1.x*a0.y + g1.y*a1.y + g1.z*a2.y + g1.w*a3.y;
        const float tmp2 = g1.x*a0.z + g1.y*a1.z + g1.z*a2.z + g1.w*a3.z;
        const float tmp3 = g1.x*a0.w + g1.y*a1.w + g1.z*a2.w + g1.w*a3.w;

        // out[e] = sum_s temp[s] * g3[s][e0+e]
        const float* p3 = B3 + ko;
        const float4 b0 = *reinterpret_cast<const float4*>(p3);
        const float4 b1 = *reinterpret_cast<const float4*>(p3 +     V3*D3);
        const float4 b2 = *reinterpret_cast<const float4*>(p3 + 2 * V3*D3);
        const float4 b3 = *reinterpret_cast<const float4*>(p3 + 3 * V3*D3);
        float4 o;
        o.x = tmp0*b0.x + tmp1*b1.x + tmp2*b2.x + tmp3*b3.x;
        o.y = tmp0*b0.y + tmp1*b1.y + tmp2*b2.y + tmp3*b3.y;
        o.z = tmp0*b0.z + tmp1*b1.z + tmp2*b2.z + tmp3*b3.z;
        o.w = tmp0*b0.w + tmp1*b1.w + tmp2*b2.w + tmp3*b3.w;

        *reinterpret_cast<float4*>(outp) = o;
        outp += 256;
    }
}

extern "C" void kernel_launch(void* const* d_in, const int* in_sizes, int n_in,
                              void* d_out, int out_size, void* d_ws, size_t ws_size,
                              hipStream_t stream) {
    const int*   ids = (const int*)d_in[0];
    const float* cr1 = (const float*)d_in[1];
    const float* cr2 = (const float*)d_in[2];
    const float* cr3 = (const float*)d_in[3];
    const float* ci1 = (const float*)d_in[4];
    const float* ci2 = (const float*)d_in[5];
    const float* ci3 = (const float*)d_in[6];
    float* out = (float*)d_out;

    const int N = in_sizes[0];                         // B*S tokens
    const int tokens_per_block = (BLOCK / 64) * TPW;   // 128
    const int blocks = (N + tokens_per_block - 1) / tokens_per_block;  // 1024 @ N=131072

    tt_embed_kernel<<<blocks, BLOCK, 0, stream>>>(ids, cr1, cr2, cr3, ci1, ci2, ci3, out, N);
}